// Round 1
// baseline (2131.387 us; speedup 1.0000x reference)
//
#include <hip/hip_runtime.h>
#include <math.h>

#define C 384
#define NF 16
#define H 256
#define Bb 4
#define Kk 2048
#define Nn 16384
#define MT 32           // nodes per block
#define PAD 4
#define LDW (C + PAD)   // 388 floats: breaks 384-stride bank aliasing, keeps 16B align

// ---------------- LayerNorm over rows of x (width C), in place ----------------
__device__ inline void ln_rows(float (*x)[LDW], const float* __restrict__ gw,
                               const float* __restrict__ bw,
                               float (*red)[8], float (*red2)[8], int tid)
{
    int m = tid >> 3, j = tid & 7;
    float s = 0.f, s2 = 0.f;
    for (int c = j; c < C; c += 8) { float v = x[m][c]; s += v; s2 += v * v; }
    red[m][j] = s; red2[m][j] = s2;
    __syncthreads();
    if (j == 0) {
        float ss = 0.f, ss2 = 0.f;
        #pragma unroll
        for (int q = 0; q < 8; ++q) { ss += red[m][q]; ss2 += red2[m][q]; }
        float mean = ss * (1.0f / C);
        float var  = ss2 * (1.0f / C) - mean * mean;
        red[m][0]  = mean;
        red2[m][0] = rsqrtf(var + 1e-5f);
    }
    __syncthreads();
    float mean = red[m][0], rstd = red2[m][0];
    for (int c = j; c < C; c += 8) {
        x[m][c] = (x[m][c] - mean) * rstd * gw[c] + bw[c];
    }
    __syncthreads();
}

// ---------------- FC layer: xout[m][f] = act(xin[m][:KD] @ W[f][:KD] + b[f]) --
template<int KD, int DD, bool DOSILU, bool DOMASK>
__device__ inline void fc_layer(const float* __restrict__ W, const float* __restrict__ bias,
                                const float (*xin)[LDW], float (*xout)[LDW],
                                const float* maskv, int tid)
{
    constexpr int F2 = DD / 2;             // feature pairs
    constexpr int TASKS = F2 * (MT / 4);   // x 8 node-groups of 4
    for (int task = tid; task < TASKS; task += 256) {
        int f0 = (task >> 3) * 2;
        int ng = (task & 7) * 4;
        float acc0[4] = {0.f, 0.f, 0.f, 0.f};
        float acc1[4] = {0.f, 0.f, 0.f, 0.f};
        const float* w0 = W + f0 * KD;
        const float* w1 = w0 + KD;
        #pragma unroll 2
        for (int k = 0; k < KD; k += 4) {
            float4 wa = *(const float4*)(w0 + k);
            float4 wb = *(const float4*)(w1 + k);
            #pragma unroll
            for (int n = 0; n < 4; ++n) {
                float4 xv = *(const float4*)(&xin[ng + n][k]);
                acc0[n] += xv.x * wa.x + xv.y * wa.y + xv.z * wa.z + xv.w * wa.w;
                acc1[n] += xv.x * wb.x + xv.y * wb.y + xv.z * wb.z + xv.w * wb.w;
            }
        }
        #pragma unroll
        for (int p = 0; p < 2; ++p) {
            float bv = bias[f0 + p];
            float* ac = (p == 0) ? acc0 : acc1;
            #pragma unroll
            for (int n = 0; n < 4; ++n) {
                float v = ac[n] + bv;
                if (DOSILU) v = v / (1.f + __expf(-v));
                if (DOMASK) v = v * maskv[ng + n];
                xout[ng + n][f0 + p] = v;
            }
        }
    }
}

__global__ __launch_bounds__(256) void upxi_kernel(
    const float* __restrict__ s_parent, const float* __restrict__ mu_k,
    const float* __restrict__ R_k,      const float* __restrict__ s_k,
    const int*   __restrict__ a_idx,    const float* __restrict__ node_mask,
    const float* __restrict__ pos01,
    const float* __restrict__ pos_w,    const float* __restrict__ pos_b,
    const float* __restrict__ q_ln_g,   const float* __restrict__ q_ln_b,
    const float* __restrict__ q_w1,     const float* __restrict__ q_b1,
    const float* __restrict__ q_w2,     const float* __restrict__ q_b2,
    const float* __restrict__ m_ln_g,   const float* __restrict__ m_ln_b,
    const float* __restrict__ m_w1,     const float* __restrict__ m_b1,
    const float* __restrict__ m_w2,     const float* __restrict__ m_b2,
    const float* __restrict__ m_w3,     const float* __restrict__ m_b3,
    float* __restrict__ out)
{
    __shared__ float xs[MT][LDW];
    __shared__ float ys[MT][LDW];
    __shared__ float feats[MT][2 * NF];
    __shared__ float red[MT][8];
    __shared__ float red2[MT][8];
    __shared__ float maskv[MT], posv[MT];
    __shared__ int   idxv[MT];
    __shared__ float xi[MT][3];

    int tid = threadIdx.x;
    long g0 = (long)blockIdx.x * MT;
    int b  = (int)(g0 / Nn);
    int n0 = (int)(g0 % Nn);

    // -------- per-node scalars --------
    if (tid < MT) {
        int gi = b * Nn + n0 + tid;
        int idx = a_idx[gi];
        idx = min(max(idx, 0), Kk - 1);
        idxv[tid]  = idx;
        maskv[tid] = node_mask[gi];
        posv[tid]  = pos01[gi];
    }
    __syncthreads();

    // -------- fourier features: [sin(ang_j), cos(ang_j)], ang = pos01 * 2^j * pi --------
    for (int t = tid; t < MT * NF; t += 256) {
        int m = t / NF, j = t % NF;
        float freq = (float)(1 << j) * 3.14159265358979323846f;
        float ang = posv[m] * freq;
        feats[m][j]      = sinf(ang);
        feats[m][NF + j] = cosf(ang);
    }
    __syncthreads();

    // -------- s_pi = gather(s_parent) + (feats @ pos_w^T + pos_b) * mask --------
    for (int t = tid; t < MT * C; t += 256) {
        int m = t / C, c = t % C;
        const float* wrow = pos_w + c * (2 * NF);
        float acc = 0.f;
        #pragma unroll
        for (int k = 0; k < 2 * NF; ++k) acc += feats[m][k] * wrow[k];
        float pe = (acc + pos_b[c]) * maskv[m];
        xs[m][c] = s_parent[((long)b * Kk + idxv[m]) * C + c] + pe;
    }
    __syncthreads();

    // -------- q_proj: LN -> Linear+SiLU -> Linear, * mask --------
    ln_rows(xs, q_ln_g, q_ln_b, red, red2, tid);
    fc_layer<C, C, true,  false>(q_w1, q_b1, xs, ys, maskv, tid);
    __syncthreads();
    fc_layer<C, C, false, true >(q_w2, q_b2, ys, xs, maskv, tid);
    __syncthreads();

    // -------- mlp: LN -> Linear(C,H)+SiLU -> Linear(H,H)+SiLU --------
    ln_rows(xs, m_ln_g, m_ln_b, red, red2, tid);
    fc_layer<C, H, true, false>(m_w1, m_b1, xs, ys, maskv, tid);
    __syncthreads();
    fc_layer<H, H, true, false>(m_w2, m_b2, ys, xs, maskv, tid);
    __syncthreads();

    // -------- final Linear(H,3), mask, tanh * 1.5 --------
    if (tid < MT * 3) {
        int m = tid / 3, j = tid % 3;
        const float* wr = m_w3 + j * H;
        float acc = 0.f;
        for (int k = 0; k < H; ++k) acc += xs[m][k] * wr[k];
        float v = (acc + m_b3[j]) * maskv[m];
        xi[m][j] = tanhf(v) * 1.5f;
    }
    __syncthreads();

    // -------- rigid apply + outputs --------
    if (tid < MT) {
        int m = tid;
        long gi = (long)b * Nn + n0 + m;
        long pk = (long)b * Kk + idxv[m];
        float xv[3], yv[3];
        #pragma unroll
        for (int j = 0; j < 3; ++j) {
            float sc = fmaxf(s_k[pk * 3 + j], 1e-8f);
            xv[j] = xi[m][j] * sc;
        }
        #pragma unroll
        for (int i = 0; i < 3; ++i) {
            float a = R_k[pk * 9 + i * 3 + 0] * xv[0]
                    + R_k[pk * 9 + i * 3 + 1] * xv[1]
                    + R_k[pk * 9 + i * 3 + 2] * xv[2]
                    + mu_k[pk * 3 + i];
            yv[i] = a * maskv[m] * 10.f;
        }
        float* o0 = out;                       // xi_hat   [B,N,3]
        float* o1 = out + (long)Bb * Nn * 3;   // x_hat*10 [B,N,3]
        float* o2 = out + (long)Bb * Nn * 6;   // pos01    [B,N]
        #pragma unroll
        for (int j = 0; j < 3; ++j) { o0[gi * 3 + j] = xi[m][j]; o1[gi * 3 + j] = yv[j]; }
        o2[gi] = posv[m];
    }
}

extern "C" void kernel_launch(void* const* d_in, const int* in_sizes, int n_in,
                              void* d_out, int out_size, void* d_ws, size_t ws_size,
                              hipStream_t stream) {
    const float* s_parent = (const float*)d_in[0];
    const float* mu_k     = (const float*)d_in[1];
    const float* R_k      = (const float*)d_in[2];
    const float* s_k      = (const float*)d_in[3];
    const int*   a_idx    = (const int*)  d_in[4];
    const float* node_mask= (const float*)d_in[5];
    const float* pos01    = (const float*)d_in[6];
    const float* pos_w    = (const float*)d_in[7];
    const float* pos_b    = (const float*)d_in[8];
    const float* q_ln_g   = (const float*)d_in[9];
    const float* q_ln_b   = (const float*)d_in[10];
    const float* q_w1     = (const float*)d_in[11];
    const float* q_b1     = (const float*)d_in[12];
    const float* q_w2     = (const float*)d_in[13];
    const float* q_b2     = (const float*)d_in[14];
    const float* m_ln_g   = (const float*)d_in[15];
    const float* m_ln_b   = (const float*)d_in[16];
    const float* m_w1     = (const float*)d_in[17];
    const float* m_b1     = (const float*)d_in[18];
    const float* m_w2     = (const float*)d_in[19];
    const float* m_b2     = (const float*)d_in[20];
    const float* m_w3     = (const float*)d_in[21];
    const float* m_b3     = (const float*)d_in[22];

    int blocks = (Bb * Nn) / MT;  // 2048
    upxi_kernel<<<blocks, 256, 0, stream>>>(
        s_parent, mu_k, R_k, s_k, a_idx, node_mask, pos01,
        pos_w, pos_b, q_ln_g, q_ln_b, q_w1, q_b1, q_w2, q_b2,
        m_ln_g, m_ln_b, m_w1, m_b1, m_w2, m_b2, m_w3, m_b3,
        (float*)d_out);
}

// Round 2
// 387.718 us; speedup vs baseline: 5.4973x; 5.4973x over previous
//
#include <hip/hip_runtime.h>
#include <math.h>

#define C 384
#define NF 16
#define H 256
#define Bb 4
#define Kk 2048
#define Nn 16384
#define MT 32            // nodes per block
#define LDA 392          // bf16 row stride: 392*2B=784B => 196 words => +4 banks/row (free 2-way)

typedef __attribute__((ext_vector_type(8))) short bf16x8;
typedef __attribute__((ext_vector_type(4))) float f32x4;

// ws layout (shorts)
#define POS_OFF 0
#define Q1_OFF  12288
#define Q2_OFF  159744
#define M1_OFF  307200
#define M2_OFF  405504
#define W_TOTAL 471040

__device__ inline short f2bf(float x) {
    union { float f; unsigned u; } v; v.f = x;
    unsigned r = (v.u + 0x7FFFu + ((v.u >> 16) & 1u)) >> 16;
    return (short)r;
}
__device__ inline float bf2f(short s) {
    union { unsigned u; float f; } v; v.u = ((unsigned)(unsigned short)s) << 16;
    return v.f;
}

// ---------------- weight f32->bf16 conversion into workspace ----------------
__global__ __launch_bounds__(256) void conv_w(
    const float* __restrict__ pos_w, const float* __restrict__ q_w1,
    const float* __restrict__ q_w2,  const float* __restrict__ m_w1,
    const float* __restrict__ m_w2,  short* __restrict__ ws)
{
    int i = blockIdx.x * 256 + threadIdx.x;
    if (i >= W_TOTAL) return;
    float v;
    if      (i < Q1_OFF) v = pos_w[i - POS_OFF];
    else if (i < Q2_OFF) v = q_w1[i - Q1_OFF];
    else if (i < M1_OFF) v = q_w2[i - Q2_OFF];
    else if (i < M2_OFF) v = m_w1[i - M1_OFF];
    else                 v = m_w2[i - M2_OFF];
    ws[i] = f2bf(v);
}

// ---------------- LayerNorm over bf16 rows (width C), in place ----------------
__device__ inline void ln_bf(short (*x)[LDA], const float* __restrict__ gw,
                             const float* __restrict__ bw,
                             float (*red)[8], float (*red2)[8], int tid)
{
    int m = tid >> 3, j = tid & 7;
    float s = 0.f, s2 = 0.f;
    for (int c = j; c < C; c += 8) { float v = bf2f(x[m][c]); s += v; s2 += v * v; }
    red[m][j] = s; red2[m][j] = s2;
    __syncthreads();
    if (j == 0) {
        float ss = 0.f, ss2 = 0.f;
        #pragma unroll
        for (int q = 0; q < 8; ++q) { ss += red[m][q]; ss2 += red2[m][q]; }
        float mean = ss * (1.0f / C);
        float var  = ss2 * (1.0f / C) - mean * mean;
        red[m][0]  = mean;
        red2[m][0] = rsqrtf(var + 1e-5f);
    }
    __syncthreads();
    float mean = red[m][0], rstd = red2[m][0];
    for (int c = j; c < C; c += 8) {
        float v = (bf2f(x[m][c]) - mean) * rstd * gw[c] + bw[c];
        x[m][c] = f2bf(v);
    }
    __syncthreads();
}

// ---------------- MFMA FC layer: out[m][f] = act(in[m][:K] @ W[f][:K] + b[f]) --
// wave handles features [wave*NTILES*16, ...); M=32 nodes = 2 m-tiles of 16.
template<int K, int NTILES, bool SILU, bool MASK>
__device__ inline void fc_mfma(const short* __restrict__ W, const float* __restrict__ bias,
                               const short (*in)[LDA], short (*out)[LDA],
                               const float* maskv, int wave, int lane)
{
    const int q  = lane >> 4;
    const int ln = lane & 15;
    const int fbase = wave * NTILES * 16;
    f32x4 acc[2][NTILES];
    #pragma unroll
    for (int mt = 0; mt < 2; ++mt)
        #pragma unroll
        for (int nt = 0; nt < NTILES; ++nt)
            acc[mt][nt] = (f32x4){0.f, 0.f, 0.f, 0.f};

    #pragma unroll 2
    for (int kk = 0; kk < K; kk += 32) {
        int ko = kk + q * 8;
        bf16x8 a0 = *(const bf16x8*)&in[ln][ko];
        bf16x8 a1 = *(const bf16x8*)&in[16 + ln][ko];
        #pragma unroll
        for (int nt = 0; nt < NTILES; ++nt) {
            int f = fbase + nt * 16 + ln;
            bf16x8 bfr = *(const bf16x8*)&W[f * K + ko];
            acc[0][nt] = __builtin_amdgcn_mfma_f32_16x16x32_bf16(a0, bfr, acc[0][nt], 0, 0, 0);
            acc[1][nt] = __builtin_amdgcn_mfma_f32_16x16x32_bf16(a1, bfr, acc[1][nt], 0, 0, 0);
        }
    }

    #pragma unroll
    for (int nt = 0; nt < NTILES; ++nt) {
        int f = fbase + nt * 16 + ln;
        float bv = bias[f];
        #pragma unroll
        for (int mt = 0; mt < 2; ++mt) {
            #pragma unroll
            for (int r = 0; r < 4; ++r) {
                int m = mt * 16 + q * 4 + r;
                float v = acc[mt][nt][r] + bv;
                if (SILU) v = v / (1.f + __expf(-v));
                if (MASK) v *= maskv[m];
                out[m][f] = f2bf(v);
            }
        }
    }
}

__global__ __launch_bounds__(256, 3) void upxi_mfma(
    const float* __restrict__ s_parent, const float* __restrict__ mu_k,
    const float* __restrict__ R_k,      const float* __restrict__ s_k,
    const int*   __restrict__ a_idx,    const float* __restrict__ node_mask,
    const float* __restrict__ pos01,
    const float* __restrict__ pos_b,
    const float* __restrict__ q_ln_g,   const float* __restrict__ q_ln_b,
    const float* __restrict__ q_b1,     const float* __restrict__ q_b2,
    const float* __restrict__ m_ln_g,   const float* __restrict__ m_ln_b,
    const float* __restrict__ m_b1,     const float* __restrict__ m_b2,
    const float* __restrict__ m_w3,     const float* __restrict__ m_b3,
    const short* __restrict__ wsb,
    float* __restrict__ out)
{
    __shared__ short xa[MT][LDA];
    __shared__ short ya[MT][LDA];
    __shared__ float red[MT][8];
    __shared__ float red2[MT][8];
    __shared__ float maskv[MT], posv[MT];
    __shared__ int   idxv[MT];
    __shared__ float xi[MT][3];

    short* featb = &ya[0][0];   // [32 nodes][stride 40] bf16, overlays ya (free until q_w1 output)

    int tid  = threadIdx.x;
    int wave = tid >> 6;
    int lane = tid & 63;
    long g0 = (long)blockIdx.x * MT;
    int b  = (int)(g0 / Nn);
    int n0 = (int)(g0 % Nn);

    // -------- per-node scalars --------
    if (tid < MT) {
        int gi = b * Nn + n0 + tid;
        int idx = a_idx[gi];
        idx = min(max(idx, 0), Kk - 1);
        idxv[tid]  = idx;
        maskv[tid] = node_mask[gi];
        posv[tid]  = pos01[gi];
    }
    __syncthreads();

    // -------- fourier features (bf16, row stride 40): sin | cos --------
    for (int t = tid; t < MT * NF; t += 256) {
        int m = t >> 4, j = t & 15;
        float freq = (float)(1 << j) * 3.14159265358979323846f;
        float ang = posv[m] * freq;
        float sv, cv;
        __sincosf(ang, &sv, &cv);
        featb[m * 40 + j]      = f2bf(sv);
        featb[m * 40 + 16 + j] = f2bf(cv);
    }
    __syncthreads();

    // -------- pos_emb MFMA (K=32, one k-step) + gather epilogue -> xa = s_pi --------
    {
        const short* pos_wb = wsb + POS_OFF;
        const int q = lane >> 4, ln = lane & 15;
        int ko = q * 8;
        f32x4 pacc[2][6];
        #pragma unroll
        for (int mt = 0; mt < 2; ++mt)
            #pragma unroll
            for (int nt = 0; nt < 6; ++nt)
                pacc[mt][nt] = (f32x4){0.f, 0.f, 0.f, 0.f};
        bf16x8 a0 = *(const bf16x8*)&featb[(ln)      * 40 + ko];
        bf16x8 a1 = *(const bf16x8*)&featb[(16 + ln) * 40 + ko];
        #pragma unroll
        for (int nt = 0; nt < 6; ++nt) {
            int f = wave * 96 + nt * 16 + ln;
            bf16x8 bfr = *(const bf16x8*)&pos_wb[f * 32 + ko];
            pacc[0][nt] = __builtin_amdgcn_mfma_f32_16x16x32_bf16(a0, bfr, pacc[0][nt], 0, 0, 0);
            pacc[1][nt] = __builtin_amdgcn_mfma_f32_16x16x32_bf16(a1, bfr, pacc[1][nt], 0, 0, 0);
        }
        __syncthreads();   // featb (in ya) fully consumed before later ya writes
        #pragma unroll
        for (int nt = 0; nt < 6; ++nt) {
            int f = wave * 96 + nt * 16 + ln;
            float pb = pos_b[f];
            #pragma unroll
            for (int mt = 0; mt < 2; ++mt) {
                #pragma unroll
                for (int r = 0; r < 4; ++r) {
                    int m = mt * 16 + q * 4 + r;
                    float v = (pacc[mt][nt][r] + pb) * maskv[m]
                            + s_parent[((long)b * Kk + idxv[m]) * C + f];
                    xa[m][f] = f2bf(v);
                }
            }
        }
    }
    __syncthreads();

    // -------- q_proj: LN -> Linear+SiLU -> Linear*mask --------
    ln_bf(xa, q_ln_g, q_ln_b, red, red2, tid);
    fc_mfma<C, 6, true,  false>(wsb + Q1_OFF, q_b1, xa, ya, maskv, wave, lane);
    __syncthreads();
    fc_mfma<C, 6, false, true >(wsb + Q2_OFF, q_b2, ya, xa, maskv, wave, lane);
    __syncthreads();

    // -------- mlp: LN -> Linear(C,H)+SiLU -> Linear(H,H)+SiLU --------
    ln_bf(xa, m_ln_g, m_ln_b, red, red2, tid);
    fc_mfma<C, 4, true, false>(wsb + M1_OFF, m_b1, xa, ya, maskv, wave, lane);
    __syncthreads();
    fc_mfma<H, 4, true, false>(wsb + M2_OFF, m_b2, ya, xa, maskv, wave, lane);
    __syncthreads();

    // -------- final Linear(H,3) f32, mask, tanh*1.5 --------
    if (tid < MT * 3) {
        int m = tid / 3, j = tid % 3;
        const float* wr = m_w3 + j * H;
        float acc = 0.f;
        for (int k = 0; k < H; ++k) acc += bf2f(xa[m][k]) * wr[k];
        float v = (acc + m_b3[j]) * maskv[m];
        xi[m][j] = tanhf(v) * 1.5f;
    }
    __syncthreads();

    // -------- rigid apply + outputs --------
    if (tid < MT) {
        int m = tid;
        long gi = (long)b * Nn + n0 + m;
        long pk = (long)b * Kk + idxv[m];
        float xv[3], yv[3];
        #pragma unroll
        for (int j = 0; j < 3; ++j) {
            float sc = fmaxf(s_k[pk * 3 + j], 1e-8f);
            xv[j] = xi[m][j] * sc;
        }
        #pragma unroll
        for (int i = 0; i < 3; ++i) {
            float a = R_k[pk * 9 + i * 3 + 0] * xv[0]
                    + R_k[pk * 9 + i * 3 + 1] * xv[1]
                    + R_k[pk * 9 + i * 3 + 2] * xv[2]
                    + mu_k[pk * 3 + i];
            yv[i] = a * maskv[m] * 10.f;
        }
        float* o0 = out;
        float* o1 = out + (long)Bb * Nn * 3;
        float* o2 = out + (long)Bb * Nn * 6;
        #pragma unroll
        for (int j = 0; j < 3; ++j) { o0[gi * 3 + j] = xi[m][j]; o1[gi * 3 + j] = yv[j]; }
        o2[gi] = posv[m];
    }
}

extern "C" void kernel_launch(void* const* d_in, const int* in_sizes, int n_in,
                              void* d_out, int out_size, void* d_ws, size_t ws_size,
                              hipStream_t stream) {
    const float* s_parent = (const float*)d_in[0];
    const float* mu_k     = (const float*)d_in[1];
    const float* R_k      = (const float*)d_in[2];
    const float* s_k      = (const float*)d_in[3];
    const int*   a_idx    = (const int*)  d_in[4];
    const float* node_mask= (const float*)d_in[5];
    const float* pos01    = (const float*)d_in[6];
    const float* pos_w    = (const float*)d_in[7];
    const float* pos_b    = (const float*)d_in[8];
    const float* q_ln_g   = (const float*)d_in[9];
    const float* q_ln_b   = (const float*)d_in[10];
    const float* q_w1     = (const float*)d_in[11];
    const float* q_b1     = (const float*)d_in[12];
    const float* q_w2     = (const float*)d_in[13];
    const float* q_b2     = (const float*)d_in[14];
    const float* m_ln_g   = (const float*)d_in[15];
    const float* m_ln_b   = (const float*)d_in[16];
    const float* m_w1     = (const float*)d_in[17];
    const float* m_b1     = (const float*)d_in[18];
    const float* m_w2     = (const float*)d_in[19];
    const float* m_b2     = (const float*)d_in[20];
    const float* m_w3     = (const float*)d_in[21];
    const float* m_b3     = (const float*)d_in[22];

    short* wsb = (short*)d_ws;

    conv_w<<<(W_TOTAL + 255) / 256, 256, 0, stream>>>(pos_w, q_w1, q_w2, m_w1, m_w2, wsb);

    int blocks = (Bb * Nn) / MT;  // 2048
    upxi_mfma<<<blocks, 256, 0, stream>>>(
        s_parent, mu_k, R_k, s_k, a_idx, node_mask, pos01,
        pos_b, q_ln_g, q_ln_b, q_b1, q_b2,
        m_ln_g, m_ln_b, m_b1, m_b2, m_w3, m_b3,
        wsb, (float*)d_out);
}